// Round 5
// baseline (1011.708 us; speedup 1.0000x reference)
//
#include <hip/hip_runtime.h>
#include <hip/hip_bf16.h>
#include <math.h>

#define B_   4
#define T_   2048
#define C_   1024
#define H_   8
#define DH   128
#define DFF  4096
#define M_   (B_*T_)   // 8192 rows

typedef __attribute__((ext_vector_type(8))) short bf16x8;
typedef __attribute__((ext_vector_type(4))) float f32x4;

// sqrt(128) * log2(e): scores computed directly in exp2 domain
#define SC2 16.32223094f

__device__ __forceinline__ unsigned short f2bf(float x) {
  union { float f; unsigned u; } v; v.f = x;
  return (unsigned short)((v.u + 0x7fffu + ((v.u >> 16) & 1u)) >> 16);
}
__device__ __forceinline__ float bf2f(unsigned short h) {
  union { unsigned u; float f; } v; v.u = ((unsigned)h) << 16; return v.f;
}

__device__ __forceinline__ f32x4 mfma_bf16(bf16x8 a, bf16x8 b, f32x4 c) {
  return __builtin_amdgcn_mfma_f32_16x16x32_bf16(a, b, c, 0, 0, 0);
}

// async global->LDS, 16B per lane; HW places lane i at wave-base + i*16
__device__ __forceinline__ void gll16(const void* g, void* l) {
  __builtin_amdgcn_global_load_lds((const __attribute__((address_space(1))) void*)g,
                                   (__attribute__((address_space(3))) void*)l,
                                   16, 0, 0);
}

// ---------------------------------------------------------------------------
// LayerNorm: one block per row, 256 threads; emits hi/lo split bf16.
// ---------------------------------------------------------------------------
__global__ __launch_bounds__(256) void ln_kernel(const float* __restrict__ in,
                                                 const float* __restrict__ g,
                                                 const float* __restrict__ bb,
                                                 unsigned short* __restrict__ h_hi,
                                                 unsigned short* __restrict__ h_lo) {
  __shared__ float red[8];
  const int row = blockIdx.x;
  const int tid = threadIdx.x;
  const float* p = in + (size_t)row * C_;
  const float4 xv = *(const float4*)(p + (tid << 2));
  float s  = xv.x + xv.y + xv.z + xv.w;
  float sq = xv.x*xv.x + xv.y*xv.y + xv.z*xv.z + xv.w*xv.w;
  #pragma unroll
  for (int off = 32; off > 0; off >>= 1) {
    s  += __shfl_xor(s, off);
    sq += __shfl_xor(sq, off);
  }
  if ((tid & 63) == 0) { red[(tid >> 6) * 2] = s; red[(tid >> 6) * 2 + 1] = sq; }
  __syncthreads();
  s  = red[0] + red[2] + red[4] + red[6];
  sq = red[1] + red[3] + red[5] + red[7];
  const float mu  = s * (1.0f / C_);
  const float var = sq * (1.0f / C_) - mu * mu;
  const float rs  = rsqrtf(var + 1e-5f);
  const float4 gv = *(const float4*)(g  + (tid << 2));
  const float4 bv = *(const float4*)(bb + (tid << 2));
  float ov[4];
  ov[0] = (xv.x - mu) * rs * gv.x + bv.x;
  ov[1] = (xv.y - mu) * rs * gv.y + bv.y;
  ov[2] = (xv.z - mu) * rs * gv.z + bv.z;
  ov[3] = (xv.w - mu) * rs * gv.w + bv.w;
  ushort4 hv, lv;
  unsigned short* hp = (unsigned short*)&hv;
  unsigned short* lp = (unsigned short*)&lv;
  #pragma unroll
  for (int j = 0; j < 4; ++j) {
    hp[j] = f2bf(ov[j]);
    lp[j] = f2bf(ov[j] - bf2f(hp[j]));
  }
  *(ushort4*)(h_hi + (size_t)row * C_ + (tid << 2)) = hv;
  *(ushort4*)(h_lo + (size_t)row * C_ + (tid << 2)) = lv;
}

// ---------------------------------------------------------------------------
// Weight converters (transpose to n-major k-contiguous bf16).
// ---------------------------------------------------------------------------
__global__ __launch_bounds__(256) void cvt_t_kernel(const float* __restrict__ in,
                                                    unsigned short* __restrict__ out,
                                                    int R, int CC) {
  __shared__ float tile[32][33];
  const int r0 = blockIdx.y << 5, c0 = blockIdx.x << 5;
  const int tr = threadIdx.x >> 3, tc4 = (threadIdx.x & 7) << 2;
  const float4 vv = *(const float4*)(in + (size_t)(r0 + tr) * CC + c0 + tc4);
  tile[tr][tc4+0] = vv.x; tile[tr][tc4+1] = vv.y;
  tile[tr][tc4+2] = vv.z; tile[tr][tc4+3] = vv.w;
  __syncthreads();
  ushort4 o;
  o.x = f2bf(tile[tc4+0][tr]); o.y = f2bf(tile[tc4+1][tr]);
  o.z = f2bf(tile[tc4+2][tr]); o.w = f2bf(tile[tc4+3][tr]);
  *(ushort4*)(out + (size_t)(c0 + tr) * R + r0 + tc4) = o;
}

// split hi/lo transpose for wq/wk/wv: in [H][C][DH] -> out[z][DH][C], z=which*8+h
__global__ __launch_bounds__(256) void cvt_qkv_kernel(const float* __restrict__ wq,
                                                      const float* __restrict__ wk,
                                                      const float* __restrict__ wv,
                                                      unsigned short* __restrict__ wt_hi,
                                                      unsigned short* __restrict__ wt_lo) {
  const int z = blockIdx.z;
  const int which = z >> 3, head = z & 7;
  const float* in = (which == 0 ? wq : (which == 1 ? wk : wv)) + (size_t)head * C_ * DH;
  unsigned short* oh = wt_hi + (size_t)z * DH * C_;
  unsigned short* ol = wt_lo + (size_t)z * DH * C_;
  __shared__ float tile[32][33];
  const int r0 = blockIdx.y << 5, c0 = blockIdx.x << 5;   // r over C, c over DH
  const int tr = threadIdx.x >> 3, tc4 = (threadIdx.x & 7) << 2;
  const float4 vv = *(const float4*)(in + (size_t)(r0 + tr) * DH + c0 + tc4);
  tile[tr][tc4+0] = vv.x; tile[tr][tc4+1] = vv.y;
  tile[tr][tc4+2] = vv.z; tile[tr][tc4+3] = vv.w;
  __syncthreads();
  ushort4 hv, lv;
  unsigned short* hp = (unsigned short*)&hv;
  unsigned short* lp = (unsigned short*)&lv;
  #pragma unroll
  for (int j = 0; j < 4; ++j) {
    const float val = tile[tc4+j][tr];
    hp[j] = f2bf(val);
    lp[j] = f2bf(val - bf2f(hp[j]));
  }
  *(ushort4*)(oh + (size_t)(c0 + tr) * C_ + r0 + tc4) = hv;
  *(ushort4*)(ol + (size_t)(c0 + tr) * C_ + r0 + tc4) = lv;
}

// ---------------------------------------------------------------------------
// MFMA GEMM core: 128x128 tile, BK=32, 256 threads (4 waves, 2x2 wave grid).
// A [M][K] k-contig bf16, B [N][K] k-contig bf16.
// TERMS=3: Ah*Bh + Ah*Bl + Al*Bh split-precision.
// ---------------------------------------------------------------------------
template<int TERMS>
__device__ __forceinline__ void gemm128_mfma(
    const unsigned short* __restrict__ Ah, const unsigned short* __restrict__ Al,
    int lda,
    const unsigned short* __restrict__ Bh, const unsigned short* __restrict__ Bl,
    int ldb, int K, f32x4 (&acc)[4][4],
    unsigned short* AhS, unsigned short* AlS,
    unsigned short* BhS, unsigned short* BlS) {
  const int tid  = threadIdx.x;
  const int w    = tid >> 6;
  const int lane = tid & 63;
  const int l15  = lane & 15, quad = lane >> 4;
  const int srow = lane >> 2, skc = (lane & 3) << 3;
  const int wm = w & 1, wn = w >> 1;

  for (int k0 = 0; k0 < K; k0 += 32) {
    __syncthreads();
    #pragma unroll
    for (int i = 0; i < 2; ++i) {
      const int seg  = w * 2 + i;
      const int r    = seg * 16 + srow;
      const int lofs = seg * 512 + lane * 8;
      gll16(Ah + (size_t)r * lda + k0 + skc, AhS + lofs);
      gll16(Bh + (size_t)r * ldb + k0 + skc, BhS + lofs);
      if (TERMS == 3) {
        gll16(Al + (size_t)r * lda + k0 + skc, AlS + lofs);
        gll16(Bl + (size_t)r * ldb + k0 + skc, BlS + lofs);
      }
    }
    __syncthreads();
    bf16x8 aH[4], bH[4], aL[4], bL[4];
    #pragma unroll
    for (int t = 0; t < 4; ++t) {
      aH[t] = *(const bf16x8*)&AhS[(wm * 64 + t * 16 + l15) * 32 + quad * 8];
      bH[t] = *(const bf16x8*)&BhS[(wn * 64 + t * 16 + l15) * 32 + quad * 8];
      if (TERMS == 3) {
        aL[t] = *(const bf16x8*)&AlS[(wm * 64 + t * 16 + l15) * 32 + quad * 8];
        bL[t] = *(const bf16x8*)&BlS[(wn * 64 + t * 16 + l15) * 32 + quad * 8];
      }
    }
    #pragma unroll
    for (int rt = 0; rt < 4; ++rt)
      #pragma unroll
      for (int ct = 0; ct < 4; ++ct) {
        if (TERMS == 3) {
          acc[rt][ct] = mfma_bf16(aL[rt], bH[ct], acc[rt][ct]);
          acc[rt][ct] = mfma_bf16(aH[rt], bL[ct], acc[rt][ct]);
        }
        acc[rt][ct] = mfma_bf16(aH[rt], bH[ct], acc[rt][ct]);
      }
  }
}

// ---------------------------------------------------------------------------
// QK projection (split precision). grid = (M/128=64, 2*H=16).
// which==0: q out [bh][t][d] bf16 hi/lo, PRE-SCALED by SC2 (exp2-domain).
// which==1: k out tile-image [bh][64 kt][4 kc][32 key][32 d] bf16 hi/lo.
// ---------------------------------------------------------------------------
__global__ __launch_bounds__(256) void qkm_kernel(const unsigned short* __restrict__ h_hi,
                                                  const unsigned short* __restrict__ h_lo,
                                                  const unsigned short* __restrict__ wt_hi,
                                                  const unsigned short* __restrict__ wt_lo,
                                                  unsigned short* __restrict__ q_hi,
                                                  unsigned short* __restrict__ q_lo,
                                                  unsigned short* __restrict__ k_hi,
                                                  unsigned short* __restrict__ k_lo) {
  __shared__ __align__(16) unsigned short AhS[4096], AlS[4096];
  __shared__ __align__(16) unsigned short BhS[4096], BlS[4096];
  const int m0 = blockIdx.x << 7;
  const int z  = blockIdx.y;
  const int which = z >> 3, head = z & 7;
  f32x4 acc[4][4];
  #pragma unroll
  for (int i = 0; i < 4; ++i)
    #pragma unroll
    for (int j = 0; j < 4; ++j)
      #pragma unroll
      for (int r = 0; r < 4; ++r) acc[i][j][r] = 0.f;
  gemm128_mfma<3>(h_hi + (size_t)m0 * C_, h_lo + (size_t)m0 * C_, C_,
                  wt_hi + (size_t)z * DH * C_, wt_lo + (size_t)z * DH * C_, C_,
                  C_, acc, AhS, AlS, BhS, BlS);
  const int lane = threadIdx.x & 63, w = threadIdx.x >> 6;
  const int l15 = lane & 15, quad = lane >> 4;
  const int wm = w & 1, wn = w >> 1;
  const int bh = (m0 >> 11) * H_ + head;
  const int tbase = (m0 & (T_ - 1)) + wm * 64 + quad * 4;
  if (which == 0) {
    #pragma unroll
    for (int rt = 0; rt < 4; ++rt)
      #pragma unroll
      for (int ct = 0; ct < 4; ++ct) {
        const int d = wn * 64 + ct * 16 + l15;
        #pragma unroll
        for (int r = 0; r < 4; ++r) {
          const int t = tbase + rt * 16 + r;
          const float val = acc[rt][ct][r] * SC2;
          const unsigned short hb = f2bf(val);
          const size_t idx = ((size_t)bh * T_ + t) * DH + d;
          q_hi[idx] = hb;
          q_lo[idx] = f2bf(val - bf2f(hb));
        }
      }
  } else {
    #pragma unroll
    for (int rt = 0; rt < 4; ++rt)
      #pragma unroll
      for (int ct = 0; ct < 4; ++ct) {
        const int d = wn * 64 + ct * 16 + l15;
        #pragma unroll
        for (int r = 0; r < 4; ++r) {
          const int t = tbase + rt * 16 + r;
          const float val = acc[rt][ct][r];
          const unsigned short hb = f2bf(val);
          const size_t idx = (((size_t)bh * 64 + (t >> 5)) * 4 + (d >> 5)) * 1024
                           + (size_t)(t & 31) * 32 + (d & 31);
          k_hi[idx] = hb;
          k_lo[idx] = f2bf(val - bf2f(hb));
        }
      }
  }
}

// ---------------------------------------------------------------------------
// V projection (plain bf16). grid = (M/128=64, H=8).
// v out tile-image [bh][64 kt][128 d][32 key] bf16.
// ---------------------------------------------------------------------------
__global__ __launch_bounds__(256) void vm_kernel(const unsigned short* __restrict__ h_hi,
                                                 const unsigned short* __restrict__ wv_hi,
                                                 unsigned short* __restrict__ vimg) {
  __shared__ __align__(16) unsigned short AhS[4096], BhS[4096];
  const int m0 = blockIdx.x << 7;
  const int head = blockIdx.y;
  f32x4 acc[4][4];
  #pragma unroll
  for (int i = 0; i < 4; ++i)
    #pragma unroll
    for (int j = 0; j < 4; ++j)
      #pragma unroll
      for (int r = 0; r < 4; ++r) acc[i][j][r] = 0.f;
  gemm128_mfma<1>(h_hi + (size_t)m0 * C_, nullptr, C_,
                  wv_hi + (size_t)(16 + head) * DH * C_, nullptr, C_,
                  C_, acc, AhS, nullptr, BhS, nullptr);
  const int lane = threadIdx.x & 63, w = threadIdx.x >> 6;
  const int l15 = lane & 15, quad = lane >> 4;
  const int wm = w & 1, wn = w >> 1;
  const int bh = (m0 >> 11) * H_ + head;
  #pragma unroll
  for (int rt = 0; rt < 4; ++rt)
    #pragma unroll
    for (int ct = 0; ct < 4; ++ct) {
      const int d  = wn * 64 + ct * 16 + l15;
      const int t0 = (m0 & (T_ - 1)) + wm * 64 + rt * 16 + quad * 4;
      ushort4 pk;
      pk.x = f2bf(acc[rt][ct][0]); pk.y = f2bf(acc[rt][ct][1]);
      pk.z = f2bf(acc[rt][ct][2]); pk.w = f2bf(acc[rt][ct][3]);
      *(ushort4*)&vimg[(((size_t)bh * 64 + (t0 >> 5)) * 128 + d) * 32 + (t0 & 31)] = pk;
    }
}

// ---------------------------------------------------------------------------
// FF1: ff1 = bf16(relu(h2 @ w1 + b1)).  grid = (DFF/128=32, M/128=64)
// ---------------------------------------------------------------------------
__global__ __launch_bounds__(256) void ff1_kernel(const unsigned short* __restrict__ h2,
                                                  const unsigned short* __restrict__ w1t,
                                                  const float* __restrict__ b1,
                                                  unsigned short* __restrict__ ff1) {
  __shared__ __align__(16) unsigned short AhS[4096], BhS[4096];
  const int n0 = blockIdx.x << 7;
  const int m0 = blockIdx.y << 7;
  f32x4 acc[4][4];
  #pragma unroll
  for (int i = 0; i < 4; ++i)
    #pragma unroll
    for (int j = 0; j < 4; ++j)
      #pragma unroll
      for (int r = 0; r < 4; ++r) acc[i][j][r] = 0.f;
  gemm128_mfma<1>(h2 + (size_t)m0 * C_, nullptr, C_,
                  w1t + (size_t)n0 * C_, nullptr, C_,
                  C_, acc, AhS, nullptr, BhS, nullptr);
  const int lane = threadIdx.x & 63, w = threadIdx.x >> 6;
  const int l15 = lane & 15, quad = lane >> 4;
  const int wm = w & 1, wn = w >> 1;
  #pragma unroll
  for (int rt = 0; rt < 4; ++rt)
    #pragma unroll
    for (int ct = 0; ct < 4; ++ct) {
      const int n = n0 + wn * 64 + ct * 16 + l15;
      const float bias = b1[n];
      #pragma unroll
      for (int r = 0; r < 4; ++r) {
        const int m = m0 + wm * 64 + rt * 16 + quad * 4 + r;
        ff1[(size_t)m * DFF + n] = f2bf(fmaxf(acc[rt][ct][r] + bias, 0.f));
      }
    }
}

// ---------------------------------------------------------------------------
// FF2: out = ff1 @ w2 + b2 + xo.  grid = (C/128=8, M/128=64)
// ---------------------------------------------------------------------------
__global__ __launch_bounds__(256) void ff2_kernel(const unsigned short* __restrict__ ff1,
                                                  const unsigned short* __restrict__ w2t,
                                                  const float* __restrict__ b2,
                                                  const float* __restrict__ xo,
                                                  float* __restrict__ out) {
  __shared__ __align__(16) unsigned short AhS[4096], BhS[4096];
  const int n0 = blockIdx.x << 7;
  const int m0 = blockIdx.y << 7;
  f32x4 acc[4][4];
  #pragma unroll
  for (int i = 0; i < 4; ++i)
    #pragma unroll
    for (int j = 0; j < 4; ++j)
      #pragma unroll
      for (int r = 0; r < 4; ++r) acc[i][j][r] = 0.f;
  gemm128_mfma<1>(ff1 + (size_t)m0 * DFF, nullptr, DFF,
                  w2t + (size_t)n0 * DFF, nullptr, DFF,
                  DFF, acc, AhS, nullptr, BhS, nullptr);
  const int lane = threadIdx.x & 63, w = threadIdx.x >> 6;
  const int l15 = lane & 15, quad = lane >> 4;
  const int wm = w & 1, wn = w >> 1;
  #pragma unroll
  for (int rt = 0; rt < 4; ++rt)
    #pragma unroll
    for (int ct = 0; ct < 4; ++ct) {
      const int n = n0 + wn * 64 + ct * 16 + l15;
      const float bias = b2[n];
      #pragma unroll
      for (int r = 0; r < 4; ++r) {
        const int m = m0 + wm * 64 + rt * 16 + quad * 4 + r;
        out[(size_t)m * C_ + n] = acc[rt][ct][r] + bias + xo[(size_t)m * C_ + n];
      }
    }
}

// ---------------------------------------------------------------------------
// MFMA flash attention, split-K: each block does 1024 keys (32 tiles) and
// writes raw-O (bf16) + m + l partials. grid = (T/128=16, B*H=32, 2 parts).
// ---------------------------------------------------------------------------
#define BQ 128

__global__ __launch_bounds__(256, 4) void attn_kernel(
    const unsigned short* __restrict__ q_hi, const unsigned short* __restrict__ q_lo,
    const unsigned short* __restrict__ k_hi, const unsigned short* __restrict__ k_lo,
    const unsigned short* __restrict__ vimg,
    unsigned short* __restrict__ Opart,
    float* __restrict__ mP, float* __restrict__ lP) {
  __shared__ __align__(16) unsigned short KhS[4096];
  __shared__ __align__(16) unsigned short KlS[4096];
  __shared__ __align__(16) unsigned short VtS[4096];
  __shared__ __align__(16) unsigned short PS [4096];

  const int bh   = blockIdx.y;
  const int qt0  = blockIdx.x * BQ;
  const int part = blockIdx.z;
  const int tid  = threadIdx.x;
  const int w    = tid >> 6;
  const int lane = tid & 63;
  const int l15  = lane & 15;
  const int quad = lane >> 4;

  // ---- Q fragments (pre-scaled hi/lo bf16), direct global loads ----
  bf16x8 Qh[2][4], Ql[2][4];
  #pragma unroll
  for (int rt = 0; rt < 2; ++rt) {
    const int row = qt0 + w * 32 + rt * 16 + l15;
    #pragma unroll
    for (int kc = 0; kc < 4; ++kc) {
      const size_t off = ((size_t)bh * T_ + row) * DH + kc * 32 + quad * 8;
      Qh[rt][kc] = *(const bf16x8*)(q_hi + off);
      Ql[rt][kc] = *(const bf16x8*)(q_lo + off);
    }
  }

  f32x4 O[2][8];
  #pragma unroll
  for (int rt = 0; rt < 2; ++rt)
    #pragma unroll
    for (int n = 0; n < 8; ++n)
      #pragma unroll
      for (int r = 0; r < 4; ++r) O[rt][n][r] = 0.f;
  float m_i[2][4], l_i[2][4];
  #pragma unroll
  for (int rt = 0; rt < 2; ++rt)
    #pragma unroll
    for (int r = 0; r < 4; ++r) { m_i[rt][r] = -1e30f; l_i[rt][r] = 0.f; }

  for (int kt = part * 32; kt < part * 32 + 32; ++kt) {
    const size_t tb = ((size_t)bh * 64 + kt) * 4096;
    __syncthreads();   // prior tile's LDS reads complete
    #pragma unroll
    for (int i = 0; i < 2; ++i) {
      const int ofs = (w * 2 + i) * 512 + lane * 8;
      gll16(k_hi + tb + ofs, KhS + ofs);
      gll16(k_lo + tb + ofs, KlS + ofs);
      gll16(vimg + tb + ofs, VtS + ofs);
    }
    __syncthreads();

    // ---- S = Q K^T (3-term split precision) ----
    f32x4 S[2][2];
    #pragma unroll
    for (int rt = 0; rt < 2; ++rt)
      #pragma unroll
      for (int ct = 0; ct < 2; ++ct)
        #pragma unroll
        for (int r = 0; r < 4; ++r) S[rt][ct][r] = 0.f;
    #pragma unroll
    for (int kc = 0; kc < 4; ++kc) {
      const int o = kc * 1024 + quad * 8;
      const bf16x8 bh0 = *(const bf16x8*)&KhS[o + l15 * 32];
      const bf16x8 bh1 = *(const bf16x8*)&KhS[o + (16 + l15) * 32];
      const bf16x8 bl0 = *(const bf16x8*)&KlS[o + l15 * 32];
      const bf16x8 bl1 = *(const bf16x8*)&KlS[o + (16 + l15) * 32];
      #pragma unroll
      for (int rt = 0; rt < 2; ++rt) {
        S[rt][0] = mfma_bf16(Ql[rt][kc], bh0, S[rt][0]);
        S[rt][0] = mfma_bf16(Qh[rt][kc], bl0, S[rt][0]);
        S[rt][0] = mfma_bf16(Qh[rt][kc], bh0, S[rt][0]);
        S[rt][1] = mfma_bf16(Ql[rt][kc], bh1, S[rt][1]);
        S[rt][1] = mfma_bf16(Qh[rt][kc], bl1, S[rt][1]);
        S[rt][1] = mfma_bf16(Qh[rt][kc], bh1, S[rt][1]);
      }
    }

    // ---- online softmax, exp2 domain (scale pre-folded into q) ----
    #pragma unroll
    for (int rt = 0; rt < 2; ++rt) {
      #pragma unroll
      for (int r = 0; r < 4; ++r) {
        const float s0 = S[rt][0][r];
        const float s1 = S[rt][1][r];
        float mx = fmaxf(s0, s1);
        #pragma unroll
        for (int msk = 1; msk < 16; msk <<= 1) mx = fmaxf(mx, __shfl_xor(mx, msk));
        const float m_new = fmaxf(m_i[rt][r], mx);
        const float alpha = exp2f(m_i[rt][r] - m_new);
        m_i[rt][r] = m_new;
        const float p0 = exp2f(s0 - m_new);
        const float p1 = exp2f(s1 - m_new);
        float rs = p0 + p1;
        #pragma unroll
        for (int msk = 1; msk < 16; msk <<= 1) rs += __shfl_xor(rs, msk);
        l_i[rt][r] = l_i[rt][r] * alpha + rs;
        #pragma unroll
        for (int n = 0; n < 8; ++n) O[rt][n][r] *= alpha;
        const int prow = w * 32 + rt * 16 + quad * 4 + r;
        // truncation-pack to bf16: uniform relative bias cancels in O/l
        PS[prow * 32 + l15]      = (unsigned short)(__float_as_uint(p0) >> 16);
        PS[prow * 32 + 16 + l15] = (unsigned short)(__float_as_uint(p1) >> 16);
      }
    }
    __syncthreads();

    // ---- O += P V ----
    bf16x8 aP[2];
    #pragma unroll
    for (int rt = 0; rt < 2; ++rt)
      aP[rt] = *(const bf16x8*)&PS[(w * 32 + rt * 16 + l15) * 32 + quad * 8];
    #pragma unroll
    for (int n = 0; n < 8; ++n) {
      const bf16x8 bv = *(const bf16x8*)&VtS[(n * 16 + l15) * 32 + quad * 8];
      O[0][n] = mfma_bf16(aP[0], bv, O[0][n]);
      O[1][n] = mfma_bf16(aP[1], bv, O[1][n]);
    }
  }

  // ---- epilogue: raw O (bf16), m, l partials ----
  unsigned short* Ob = Opart + ((size_t)(part * 32 + bh)) * T_ * DH;
  float* mrow = mP + (size_t)(part * 32 + bh) * T_;
  float* lrow = lP + (size_t)(part * 32 + bh) * T_;
  #pragma unroll
  for (int rt = 0; rt < 2; ++rt) {
    #pragma unroll
    for (int r = 0; r < 4; ++r) {
      const int t = qt0 + w * 32 + rt * 16 + quad * 4 + r;
      if (l15 == 0) { mrow[t] = m_i[rt][r]; lrow[t] = l_i[rt][r]; }
      #pragma unroll
      for (int n = 0; n < 8; ++n)
        Ob[(size_t)t * DH + n * 16 + l15] = f2bf(O[rt][n][r]);
    }
  }
}

// ---------------------------------------------------------------------------
// Split-K combine: xo = x + merge(O0,O1). 8 rows/block, grid = 65536/8.
// ---------------------------------------------------------------------------
__global__ __launch_bounds__(256) void comb_kernel(
    const unsigned short* __restrict__ Opart,
    const float* __restrict__ mP, const float* __restrict__ lP,
    const float* __restrict__ x, float* __restrict__ xo) {
  const int rid = blockIdx.x * 8 + (threadIdx.x >> 5);    // bh*2048 + t
  const int d4  = (threadIdx.x & 31) << 2;
  const int bh = rid >> 11, t = rid & (T_ - 1);
  const float m0 = mP[rid], m1 = mP[rid + 32 * T_];
  const float l0 = lP[rid], l1 = lP[rid + 32 * T_];
  const float m  = fmaxf(m0, m1);
  const float a0 = exp2f(m0 - m), a1 = exp2f(m1 - m);
  const float inv = 1.0f / (l0 * a0 + l1 * a1);
  const size_t o0 = (size_t)rid * DH + d4;
  const ushort4 u0 = *(const ushort4*)(Opart + o0);
  const ushort4 u1 = *(const ushort4*)(Opart + o0 + (size_t)32 * T_ * DH);
  const int b = bh >> 3, hh = bh & 7;
  const size_t xi = ((size_t)(b * T_ + t)) * C_ + hh * DH + d4;
  const float4 xv = *(const float4*)(x + xi);
  float4 ov;
  ov.x = xv.x + (bf2f(u0.x) * a0 + bf2f(u1.x) * a1) * inv;
  ov.y = xv.y + (bf2f(u0.y) * a0 + bf2f(u1.y) * a1) * inv;
  ov.z = xv.z + (bf2f(u0.z) * a0 + bf2f(u1.z) * a1) * inv;
  ov.w = xv.w + (bf2f(u0.w) * a0 + bf2f(u1.w) * a1) * inv;
  *(float4*)(xo + xi) = ov;
}

// ---------------------------------------------------------------------------
// Workspace layout (MB offsets):
//   0-32    xo    f32 [M][C]
//   32-48   q_hi  bf16 [bh][t][d] (pre-scaled)   \
//   48-64   q_lo  bf16 [bh][t][d]                 \
//   64-80   k_hi  bf16 image [bh][64][4][32][32]   } ff1 aliases 32-96 after attn
//   80-96   k_lo  bf16 image                      /
//   96-112  vimg  bf16 image [bh][64][128][32]
//   112-144 h_hi/h_lo bf16 [M][C]  -- ALSO Opart bf16 [2][32][T][DH] during attn
//   144-152 w1t   bf16 [DFF][C]
//   152-160 w2t   bf16 [C][DFF]
//   160-166 wt_hi bf16 [3H][DH][C]
//   166-172 wt_lo bf16 [3H][DH][C]
//   172-173 mP f32 [2][32][T]
//   173-174 lP f32 [2][32][T]
// ---------------------------------------------------------------------------
extern "C" void kernel_launch(void* const* d_in, const int* in_sizes, int n_in,
                              void* d_out, int out_size, void* d_ws, size_t ws_size,
                              hipStream_t stream) {
  (void)in_sizes; (void)n_in; (void)out_size; (void)ws_size;
  const float* x     = (const float*)d_in[0];
  const float* wq    = (const float*)d_in[1];
  const float* wk    = (const float*)d_in[2];
  const float* wv    = (const float*)d_in[3];
  const float* w1    = (const float*)d_in[4];
  const float* b1    = (const float*)d_in[5];
  const float* w2    = (const float*)d_in[6];
  const float* b2    = (const float*)d_in[7];
  const float* ln1_g = (const float*)d_in[8];
  const float* ln1_b = (const float*)d_in[9];
  const float* ln2_g = (const float*)d_in[10];
  const float* ln2_b = (const float*)d_in[11];
  float* out = (float*)d_out;

  char* W = (char*)d_ws;
  float* xo = (float*)(W);
  unsigned short* q_hi  = (unsigned short*)(W + (32u  << 20));
  unsigned short* q_lo  = (unsigned short*)(W + (48u  << 20));
  unsigned short* k_hi  = (unsigned short*)(W + (64u  << 20));
  unsigned short* k_lo  = (unsigned short*)(W + (80u  << 20));
  unsigned short* vimg  = (unsigned short*)(W + (96u  << 20));
  unsigned short* ff1   = (unsigned short*)(W + (32u  << 20));   // aliases q/k
  unsigned short* h_hi  = (unsigned short*)(W + (112u << 20));
  unsigned short* h_lo  = (unsigned short*)(W + (128u << 20));
  unsigned short* Opart = (unsigned short*)(W + (112u << 20));   // aliases h during attn
  unsigned short* w1t   = (unsigned short*)(W + (144u << 20));
  unsigned short* w2t   = (unsigned short*)(W + (152u << 20));
  unsigned short* wt_hi = (unsigned short*)(W + (160u << 20));
  unsigned short* wt_lo = (unsigned short*)(W + (166u << 20));
  float*          mPf   = (float*)(W + (172u << 20));
  float*          lPf   = (float*)(W + (173u << 20));

  cvt_t_kernel<<<dim3(DFF / 32, C_ / 32), 256, 0, stream>>>(w1, w1t, C_, DFF);
  cvt_t_kernel<<<dim3(C_ / 32, DFF / 32), 256, 0, stream>>>(w2, w2t, DFF, C_);
  cvt_qkv_kernel<<<dim3(DH / 32, C_ / 32, 24), 256, 0, stream>>>(wq, wk, wv, wt_hi, wt_lo);
  ln_kernel<<<M_, 256, 0, stream>>>(x, ln1_g, ln1_b, h_hi, h_lo);
  qkm_kernel<<<dim3(M_ / 128, 16), 256, 0, stream>>>(h_hi, h_lo, wt_hi, wt_lo,
                                                     q_hi, q_lo, k_hi, k_lo);
  vm_kernel<<<dim3(M_ / 128, H_), 256, 0, stream>>>(h_hi, wt_hi, vimg);
  attn_kernel<<<dim3(T_ / BQ, B_ * H_, 2), 256, 0, stream>>>(q_hi, q_lo, k_hi, k_lo,
                                                             vimg, Opart, mPf, lPf);
  comb_kernel<<<(32 * T_) / 8, 256, 0, stream>>>(Opart, mPf, lPf, x, xo);
  ln_kernel<<<M_, 256, 0, stream>>>(xo, ln2_g, ln2_b, h_hi, h_lo);
  ff1_kernel<<<dim3(DFF / 128, M_ / 128), 256, 0, stream>>>(h_hi, w1t, b1, ff1);
  ff2_kernel<<<dim3(C_ / 128, M_ / 128), 256, 0, stream>>>(ff1, w2t, b2, xo, out);
}

// Round 6
// 740.408 us; speedup vs baseline: 1.3664x; 1.3664x over previous
//
#include <hip/hip_runtime.h>
#include <hip/hip_bf16.h>
#include <math.h>

#define B_   4
#define T_   2048
#define C_   1024
#define H_   8
#define DH   128
#define DFF  4096
#define M_   (B_*T_)   // 8192 rows

typedef __attribute__((ext_vector_type(8))) short bf16x8;
typedef __attribute__((ext_vector_type(4))) float f32x4;

// sqrt(128) * log2(e): scores computed directly in exp2 domain
#define SC2 16.32223094f

__device__ __forceinline__ unsigned short f2bf(float x) {
  union { float f; unsigned u; } v; v.f = x;
  return (unsigned short)((v.u + 0x7fffu + ((v.u >> 16) & 1u)) >> 16);
}
__device__ __forceinline__ float bf2f(unsigned short h) {
  union { unsigned u; float f; } v; v.u = ((unsigned)h) << 16; return v.f;
}

__device__ __forceinline__ f32x4 mfma_bf16(bf16x8 a, bf16x8 b, f32x4 c) {
  return __builtin_amdgcn_mfma_f32_16x16x32_bf16(a, b, c, 0, 0, 0);
}

// async global->LDS, 16B per lane; HW places lane i at wave-base + i*16
__device__ __forceinline__ void gll16(const void* g, void* l) {
  __builtin_amdgcn_global_load_lds((const __attribute__((address_space(1))) void*)g,
                                   (__attribute__((address_space(3))) void*)l,
                                   16, 0, 0);
}

// ---------------------------------------------------------------------------
// LayerNorm: one block per row, 256 threads; emits hi/lo split bf16.
// ---------------------------------------------------------------------------
__global__ __launch_bounds__(256) void ln_kernel(const float* __restrict__ in,
                                                 const float* __restrict__ g,
                                                 const float* __restrict__ bb,
                                                 unsigned short* __restrict__ h_hi,
                                                 unsigned short* __restrict__ h_lo) {
  __shared__ float red[8];
  const int row = blockIdx.x;
  const int tid = threadIdx.x;
  const float* p = in + (size_t)row * C_;
  const float4 xv = *(const float4*)(p + (tid << 2));
  float s  = xv.x + xv.y + xv.z + xv.w;
  float sq = xv.x*xv.x + xv.y*xv.y + xv.z*xv.z + xv.w*xv.w;
  #pragma unroll
  for (int off = 32; off > 0; off >>= 1) {
    s  += __shfl_xor(s, off);
    sq += __shfl_xor(sq, off);
  }
  if ((tid & 63) == 0) { red[(tid >> 6) * 2] = s; red[(tid >> 6) * 2 + 1] = sq; }
  __syncthreads();
  s  = red[0] + red[2] + red[4] + red[6];
  sq = red[1] + red[3] + red[5] + red[7];
  const float mu  = s * (1.0f / C_);
  const float var = sq * (1.0f / C_) - mu * mu;
  const float rs  = rsqrtf(var + 1e-5f);
  const float4 gv = *(const float4*)(g  + (tid << 2));
  const float4 bv = *(const float4*)(bb + (tid << 2));
  float ov[4];
  ov[0] = (xv.x - mu) * rs * gv.x + bv.x;
  ov[1] = (xv.y - mu) * rs * gv.y + bv.y;
  ov[2] = (xv.z - mu) * rs * gv.z + bv.z;
  ov[3] = (xv.w - mu) * rs * gv.w + bv.w;
  ushort4 hv, lv;
  unsigned short* hp = (unsigned short*)&hv;
  unsigned short* lp = (unsigned short*)&lv;
  #pragma unroll
  for (int j = 0; j < 4; ++j) {
    hp[j] = f2bf(ov[j]);
    lp[j] = f2bf(ov[j] - bf2f(hp[j]));
  }
  *(ushort4*)(h_hi + (size_t)row * C_ + (tid << 2)) = hv;
  *(ushort4*)(h_lo + (size_t)row * C_ + (tid << 2)) = lv;
}

// ---------------------------------------------------------------------------
// Weight converters (transpose to n-major k-contiguous bf16).
// ---------------------------------------------------------------------------
__global__ __launch_bounds__(256) void cvt_t_kernel(const float* __restrict__ in,
                                                    unsigned short* __restrict__ out,
                                                    int R, int CC) {
  __shared__ float tile[32][33];
  const int r0 = blockIdx.y << 5, c0 = blockIdx.x << 5;
  const int tr = threadIdx.x >> 3, tc4 = (threadIdx.x & 7) << 2;
  const float4 vv = *(const float4*)(in + (size_t)(r0 + tr) * CC + c0 + tc4);
  tile[tr][tc4+0] = vv.x; tile[tr][tc4+1] = vv.y;
  tile[tr][tc4+2] = vv.z; tile[tr][tc4+3] = vv.w;
  __syncthreads();
  ushort4 o;
  o.x = f2bf(tile[tc4+0][tr]); o.y = f2bf(tile[tc4+1][tr]);
  o.z = f2bf(tile[tc4+2][tr]); o.w = f2bf(tile[tc4+3][tr]);
  *(ushort4*)(out + (size_t)(c0 + tr) * R + r0 + tc4) = o;
}

// split hi/lo transpose for wq/wk/wv: in [H][C][DH] -> out[z][DH][C], z=which*8+h
__global__ __launch_bounds__(256) void cvt_qkv_kernel(const float* __restrict__ wq,
                                                      const float* __restrict__ wk,
                                                      const float* __restrict__ wv,
                                                      unsigned short* __restrict__ wt_hi,
                                                      unsigned short* __restrict__ wt_lo) {
  const int z = blockIdx.z;
  const int which = z >> 3, head = z & 7;
  const float* in = (which == 0 ? wq : (which == 1 ? wk : wv)) + (size_t)head * C_ * DH;
  unsigned short* oh = wt_hi + (size_t)z * DH * C_;
  unsigned short* ol = wt_lo + (size_t)z * DH * C_;
  __shared__ float tile[32][33];
  const int r0 = blockIdx.y << 5, c0 = blockIdx.x << 5;   // r over C, c over DH
  const int tr = threadIdx.x >> 3, tc4 = (threadIdx.x & 7) << 2;
  const float4 vv = *(const float4*)(in + (size_t)(r0 + tr) * DH + c0 + tc4);
  tile[tr][tc4+0] = vv.x; tile[tr][tc4+1] = vv.y;
  tile[tr][tc4+2] = vv.z; tile[tr][tc4+3] = vv.w;
  __syncthreads();
  ushort4 hv, lv;
  unsigned short* hp = (unsigned short*)&hv;
  unsigned short* lp = (unsigned short*)&lv;
  #pragma unroll
  for (int j = 0; j < 4; ++j) {
    const float val = tile[tc4+j][tr];
    hp[j] = f2bf(val);
    lp[j] = f2bf(val - bf2f(hp[j]));
  }
  *(ushort4*)(oh + (size_t)(c0 + tr) * C_ + r0 + tc4) = hv;
  *(ushort4*)(ol + (size_t)(c0 + tr) * C_ + r0 + tc4) = lv;
}

// ---------------------------------------------------------------------------
// MFMA GEMM core: 128x128 tile, BK=32, 256 threads (4 waves, 2x2 wave grid).
// A [M][K] k-contig bf16, B [N][K] k-contig bf16.
// TERMS=3: Ah*Bh + Ah*Bl + Al*Bh split-precision.
// ---------------------------------------------------------------------------
template<int TERMS>
__device__ __forceinline__ void gemm128_mfma(
    const unsigned short* __restrict__ Ah, const unsigned short* __restrict__ Al,
    int lda,
    const unsigned short* __restrict__ Bh, const unsigned short* __restrict__ Bl,
    int ldb, int K, f32x4 (&acc)[4][4],
    unsigned short* AhS, unsigned short* AlS,
    unsigned short* BhS, unsigned short* BlS) {
  const int tid  = threadIdx.x;
  const int w    = tid >> 6;
  const int lane = tid & 63;
  const int l15  = lane & 15, quad = lane >> 4;
  const int srow = lane >> 2, skc = (lane & 3) << 3;
  const int wm = w & 1, wn = w >> 1;

  for (int k0 = 0; k0 < K; k0 += 32) {
    __syncthreads();
    #pragma unroll
    for (int i = 0; i < 2; ++i) {
      const int seg  = w * 2 + i;
      const int r    = seg * 16 + srow;
      const int lofs = seg * 512 + lane * 8;
      gll16(Ah + (size_t)r * lda + k0 + skc, AhS + lofs);
      gll16(Bh + (size_t)r * ldb + k0 + skc, BhS + lofs);
      if (TERMS == 3) {
        gll16(Al + (size_t)r * lda + k0 + skc, AlS + lofs);
        gll16(Bl + (size_t)r * ldb + k0 + skc, BlS + lofs);
      }
    }
    __syncthreads();
    bf16x8 aH[4], bH[4], aL[4], bL[4];
    #pragma unroll
    for (int t = 0; t < 4; ++t) {
      aH[t] = *(const bf16x8*)&AhS[(wm * 64 + t * 16 + l15) * 32 + quad * 8];
      bH[t] = *(const bf16x8*)&BhS[(wn * 64 + t * 16 + l15) * 32 + quad * 8];
      if (TERMS == 3) {
        aL[t] = *(const bf16x8*)&AlS[(wm * 64 + t * 16 + l15) * 32 + quad * 8];
        bL[t] = *(const bf16x8*)&BlS[(wn * 64 + t * 16 + l15) * 32 + quad * 8];
      }
    }
    #pragma unroll
    for (int rt = 0; rt < 4; ++rt)
      #pragma unroll
      for (int ct = 0; ct < 4; ++ct) {
        if (TERMS == 3) {
          acc[rt][ct] = mfma_bf16(aL[rt], bH[ct], acc[rt][ct]);
          acc[rt][ct] = mfma_bf16(aH[rt], bL[ct], acc[rt][ct]);
        }
        acc[rt][ct] = mfma_bf16(aH[rt], bH[ct], acc[rt][ct]);
      }
  }
}

// ---------------------------------------------------------------------------
// QK projection (split precision). grid = (M/128=64, 2*H=16).
// which==0: q out [bh][t][d] bf16 hi/lo, PRE-SCALED by SC2 (exp2-domain).
// which==1: k out tile-image [bh][64 kt][4 kc][32 key][32 d] bf16 hi/lo.
// ---------------------------------------------------------------------------
__global__ __launch_bounds__(256) void qkm_kernel(const unsigned short* __restrict__ h_hi,
                                                  const unsigned short* __restrict__ h_lo,
                                                  const unsigned short* __restrict__ wt_hi,
                                                  const unsigned short* __restrict__ wt_lo,
                                                  unsigned short* __restrict__ q_hi,
                                                  unsigned short* __restrict__ q_lo,
                                                  unsigned short* __restrict__ k_hi,
                                                  unsigned short* __restrict__ k_lo) {
  __shared__ __align__(16) unsigned short AhS[4096], AlS[4096];
  __shared__ __align__(16) unsigned short BhS[4096], BlS[4096];
  const int m0 = blockIdx.x << 7;
  const int z  = blockIdx.y;
  const int which = z >> 3, head = z & 7;
  f32x4 acc[4][4];
  #pragma unroll
  for (int i = 0; i < 4; ++i)
    #pragma unroll
    for (int j = 0; j < 4; ++j)
      #pragma unroll
      for (int r = 0; r < 4; ++r) acc[i][j][r] = 0.f;
  gemm128_mfma<3>(h_hi + (size_t)m0 * C_, h_lo + (size_t)m0 * C_, C_,
                  wt_hi + (size_t)z * DH * C_, wt_lo + (size_t)z * DH * C_, C_,
                  C_, acc, AhS, AlS, BhS, BlS);
  const int lane = threadIdx.x & 63, w = threadIdx.x >> 6;
  const int l15 = lane & 15, quad = lane >> 4;
  const int wm = w & 1, wn = w >> 1;
  const int bh = (m0 >> 11) * H_ + head;
  const int tbase = (m0 & (T_ - 1)) + wm * 64 + quad * 4;
  if (which == 0) {
    #pragma unroll
    for (int rt = 0; rt < 4; ++rt)
      #pragma unroll
      for (int ct = 0; ct < 4; ++ct) {
        const int d = wn * 64 + ct * 16 + l15;
        #pragma unroll
        for (int r = 0; r < 4; ++r) {
          const int t = tbase + rt * 16 + r;
          const float val = acc[rt][ct][r] * SC2;
          const unsigned short hb = f2bf(val);
          const size_t idx = ((size_t)bh * T_ + t) * DH + d;
          q_hi[idx] = hb;
          q_lo[idx] = f2bf(val - bf2f(hb));
        }
      }
  } else {
    #pragma unroll
    for (int rt = 0; rt < 4; ++rt)
      #pragma unroll
      for (int ct = 0; ct < 4; ++ct) {
        const int d = wn * 64 + ct * 16 + l15;
        #pragma unroll
        for (int r = 0; r < 4; ++r) {
          const int t = tbase + rt * 16 + r;
          const float val = acc[rt][ct][r];
          const unsigned short hb = f2bf(val);
          const size_t idx = (((size_t)bh * 64 + (t >> 5)) * 4 + (d >> 5)) * 1024
                           + (size_t)(t & 31) * 32 + (d & 31);
          k_hi[idx] = hb;
          k_lo[idx] = f2bf(val - bf2f(hb));
        }
      }
  }
}

// ---------------------------------------------------------------------------
// V projection (plain bf16). grid = (M/128=64, H=8).
// v out tile-image [bh][64 kt][128 d][32 key] bf16.
// ---------------------------------------------------------------------------
__global__ __launch_bounds__(256) void vm_kernel(const unsigned short* __restrict__ h_hi,
                                                 const unsigned short* __restrict__ wv_hi,
                                                 unsigned short* __restrict__ vimg) {
  __shared__ __align__(16) unsigned short AhS[4096], BhS[4096];
  const int m0 = blockIdx.x << 7;
  const int head = blockIdx.y;
  f32x4 acc[4][4];
  #pragma unroll
  for (int i = 0; i < 4; ++i)
    #pragma unroll
    for (int j = 0; j < 4; ++j)
      #pragma unroll
      for (int r = 0; r < 4; ++r) acc[i][j][r] = 0.f;
  gemm128_mfma<1>(h_hi + (size_t)m0 * C_, nullptr, C_,
                  wv_hi + (size_t)(16 + head) * DH * C_, nullptr, C_,
                  C_, acc, AhS, nullptr, BhS, nullptr);
  const int lane = threadIdx.x & 63, w = threadIdx.x >> 6;
  const int l15 = lane & 15, quad = lane >> 4;
  const int wm = w & 1, wn = w >> 1;
  const int bh = (m0 >> 11) * H_ + head;
  #pragma unroll
  for (int rt = 0; rt < 4; ++rt)
    #pragma unroll
    for (int ct = 0; ct < 4; ++ct) {
      const int d  = wn * 64 + ct * 16 + l15;
      const int t0 = (m0 & (T_ - 1)) + wm * 64 + rt * 16 + quad * 4;
      ushort4 pk;
      pk.x = f2bf(acc[rt][ct][0]); pk.y = f2bf(acc[rt][ct][1]);
      pk.z = f2bf(acc[rt][ct][2]); pk.w = f2bf(acc[rt][ct][3]);
      *(ushort4*)&vimg[(((size_t)bh * 64 + (t0 >> 5)) * 128 + d) * 32 + (t0 & 31)] = pk;
    }
}

// ---------------------------------------------------------------------------
// FF1: ff1 = bf16(relu(h2 @ w1 + b1)).  grid = (DFF/128=32, M/128=64)
// ---------------------------------------------------------------------------
__global__ __launch_bounds__(256) void ff1_kernel(const unsigned short* __restrict__ h2,
                                                  const unsigned short* __restrict__ w1t,
                                                  const float* __restrict__ b1,
                                                  unsigned short* __restrict__ ff1) {
  __shared__ __align__(16) unsigned short AhS[4096], BhS[4096];
  const int n0 = blockIdx.x << 7;
  const int m0 = blockIdx.y << 7;
  f32x4 acc[4][4];
  #pragma unroll
  for (int i = 0; i < 4; ++i)
    #pragma unroll
    for (int j = 0; j < 4; ++j)
      #pragma unroll
      for (int r = 0; r < 4; ++r) acc[i][j][r] = 0.f;
  gemm128_mfma<1>(h2 + (size_t)m0 * C_, nullptr, C_,
                  w1t + (size_t)n0 * C_, nullptr, C_,
                  C_, acc, AhS, nullptr, BhS, nullptr);
  const int lane = threadIdx.x & 63, w = threadIdx.x >> 6;
  const int l15 = lane & 15, quad = lane >> 4;
  const int wm = w & 1, wn = w >> 1;
  #pragma unroll
  for (int rt = 0; rt < 4; ++rt)
    #pragma unroll
    for (int ct = 0; ct < 4; ++ct) {
      const int n = n0 + wn * 64 + ct * 16 + l15;
      const float bias = b1[n];
      #pragma unroll
      for (int r = 0; r < 4; ++r) {
        const int m = m0 + wm * 64 + rt * 16 + quad * 4 + r;
        ff1[(size_t)m * DFF + n] = f2bf(fmaxf(acc[rt][ct][r] + bias, 0.f));
      }
    }
}

// ---------------------------------------------------------------------------
// FF2: out = ff1 @ w2 + b2 + xo.  grid = (C/128=8, M/128=64)
// ---------------------------------------------------------------------------
__global__ __launch_bounds__(256) void ff2_kernel(const unsigned short* __restrict__ ff1,
                                                  const unsigned short* __restrict__ w2t,
                                                  const float* __restrict__ b2,
                                                  const float* __restrict__ xo,
                                                  float* __restrict__ out) {
  __shared__ __align__(16) unsigned short AhS[4096], BhS[4096];
  const int n0 = blockIdx.x << 7;
  const int m0 = blockIdx.y << 7;
  f32x4 acc[4][4];
  #pragma unroll
  for (int i = 0; i < 4; ++i)
    #pragma unroll
    for (int j = 0; j < 4; ++j)
      #pragma unroll
      for (int r = 0; r < 4; ++r) acc[i][j][r] = 0.f;
  gemm128_mfma<1>(ff1 + (size_t)m0 * DFF, nullptr, DFF,
                  w2t + (size_t)n0 * DFF, nullptr, DFF,
                  DFF, acc, AhS, nullptr, BhS, nullptr);
  const int lane = threadIdx.x & 63, w = threadIdx.x >> 6;
  const int l15 = lane & 15, quad = lane >> 4;
  const int wm = w & 1, wn = w >> 1;
  #pragma unroll
  for (int rt = 0; rt < 4; ++rt)
    #pragma unroll
    for (int ct = 0; ct < 4; ++ct) {
      const int n = n0 + wn * 64 + ct * 16 + l15;
      const float bias = b2[n];
      #pragma unroll
      for (int r = 0; r < 4; ++r) {
        const int m = m0 + wm * 64 + rt * 16 + quad * 4 + r;
        out[(size_t)m * C_ + n] = acc[rt][ct][r] + bias + xo[(size_t)m * C_ + n];
      }
    }
}

// ---------------------------------------------------------------------------
// MFMA flash attention, split-K: each block does 1024 keys (32 tiles) and
// writes raw-O (bf16) + m + l partials. grid = (T/128=16, B*H=32, 2 parts).
// launch_bounds (256,2): proven no-spill allocation point (120 VGPR); with
// grid=1024 the HW reaches 4 blocks/CU on its own (120<=128 => 4 waves/SIMD).
// ---------------------------------------------------------------------------
#define BQ 128

__global__ __launch_bounds__(256, 2) void attn_kernel(
    const unsigned short* __restrict__ q_hi, const unsigned short* __restrict__ q_lo,
    const unsigned short* __restrict__ k_hi, const unsigned short* __restrict__ k_lo,
    const unsigned short* __restrict__ vimg,
    unsigned short* __restrict__ Opart,
    float* __restrict__ mP, float* __restrict__ lP) {
  __shared__ __align__(16) unsigned short KhS[4096];
  __shared__ __align__(16) unsigned short KlS[4096];
  __shared__ __align__(16) unsigned short VtS[4096];
  __shared__ __align__(16) unsigned short PS [4096];

  const int bh   = blockIdx.y;
  const int qt0  = blockIdx.x * BQ;
  const int part = blockIdx.z;
  const int tid  = threadIdx.x;
  const int w    = tid >> 6;
  const int lane = tid & 63;
  const int l15  = lane & 15;
  const int quad = lane >> 4;

  // ---- Q fragments (pre-scaled hi/lo bf16), direct global loads ----
  bf16x8 Qh[2][4], Ql[2][4];
  #pragma unroll
  for (int rt = 0; rt < 2; ++rt) {
    const int row = qt0 + w * 32 + rt * 16 + l15;
    #pragma unroll
    for (int kc = 0; kc < 4; ++kc) {
      const size_t off = ((size_t)bh * T_ + row) * DH + kc * 32 + quad * 8;
      Qh[rt][kc] = *(const bf16x8*)(q_hi + off);
      Ql[rt][kc] = *(const bf16x8*)(q_lo + off);
    }
  }

  f32x4 O[2][8];
  #pragma unroll
  for (int rt = 0; rt < 2; ++rt)
    #pragma unroll
    for (int n = 0; n < 8; ++n)
      #pragma unroll
      for (int r = 0; r < 4; ++r) O[rt][n][r] = 0.f;
  float m_i[2][4], l_i[2][4];
  #pragma unroll
  for (int rt = 0; rt < 2; ++rt)
    #pragma unroll
    for (int r = 0; r < 4; ++r) { m_i[rt][r] = -1e30f; l_i[rt][r] = 0.f; }

  for (int kt = part * 32; kt < part * 32 + 32; ++kt) {
    const size_t tb = ((size_t)bh * 64 + kt) * 4096;
    __syncthreads();   // prior tile's LDS reads complete
    #pragma unroll
    for (int i = 0; i < 2; ++i) {
      const int ofs = (w * 2 + i) * 512 + lane * 8;
      gll16(k_hi + tb + ofs, KhS + ofs);
      gll16(k_lo + tb + ofs, KlS + ofs);
      gll16(vimg + tb + ofs, VtS + ofs);
    }
    __syncthreads();

    // ---- S = Q K^T (3-term split precision) ----
    f32x4 S[2][2];
    #pragma unroll
    for (int rt = 0; rt < 2; ++rt)
      #pragma unroll
      for (int ct = 0; ct < 2; ++ct)
        #pragma unroll
        for (int r = 0; r < 4; ++r) S[rt][ct][r] = 0.f;
    #pragma unroll
    for (int kc = 0; kc < 4; ++kc) {
      const int o = kc * 1024 + quad * 8;
      const bf16x8 bh0 = *(const bf16x8*)&KhS[o + l15 * 32];
      const bf16x8 bh1 = *(const bf16x8*)&KhS[o + (16 + l15) * 32];
      const bf16x8 bl0 = *(const bf16x8*)&KlS[o + l15 * 32];
      const bf16x8 bl1 = *(const bf16x8*)&KlS[o + (16 + l15) * 32];
      #pragma unroll
      for (int rt = 0; rt < 2; ++rt) {
        S[rt][0] = mfma_bf16(Ql[rt][kc], bh0, S[rt][0]);
        S[rt][0] = mfma_bf16(Qh[rt][kc], bl0, S[rt][0]);
        S[rt][0] = mfma_bf16(Qh[rt][kc], bh0, S[rt][0]);
        S[rt][1] = mfma_bf16(Ql[rt][kc], bh1, S[rt][1]);
        S[rt][1] = mfma_bf16(Qh[rt][kc], bl1, S[rt][1]);
        S[rt][1] = mfma_bf16(Qh[rt][kc], bh1, S[rt][1]);
      }
    }

    // ---- online softmax, exp2 domain (scale pre-folded into q) ----
    #pragma unroll
    for (int rt = 0; rt < 2; ++rt) {
      #pragma unroll
      for (int r = 0; r < 4; ++r) {
        const float s0 = S[rt][0][r];
        const float s1 = S[rt][1][r];
        float mx = fmaxf(s0, s1);
        #pragma unroll
        for (int msk = 1; msk < 16; msk <<= 1) mx = fmaxf(mx, __shfl_xor(mx, msk));
        const float m_new = fmaxf(m_i[rt][r], mx);
        const float alpha = exp2f(m_i[rt][r] - m_new);
        m_i[rt][r] = m_new;
        const float p0 = exp2f(s0 - m_new);
        const float p1 = exp2f(s1 - m_new);
        float rs = p0 + p1;
        #pragma unroll
        for (int msk = 1; msk < 16; msk <<= 1) rs += __shfl_xor(rs, msk);
        l_i[rt][r] = l_i[rt][r] * alpha + rs;
        #pragma unroll
        for (int n = 0; n < 8; ++n) O[rt][n][r] *= alpha;
        const int prow = w * 32 + rt * 16 + quad * 4 + r;
        // truncation-pack to bf16: uniform relative bias cancels in O/l
        PS[prow * 32 + l15]      = (unsigned short)(__float_as_uint(p0) >> 16);
        PS[prow * 32 + 16 + l15] = (unsigned short)(__float_as_uint(p1) >> 16);
      }
    }
    __syncthreads();

    // ---- O += P V ----
    bf16x8 aP[2];
    #pragma unroll
    for (int rt = 0; rt < 2; ++rt)
      aP[rt] = *(const bf16x8*)&PS[(w * 32 + rt * 16 + l15) * 32 + quad * 8];
    #pragma unroll
    for (int n = 0; n < 8; ++n) {
      const bf16x8 bv = *(const bf16x8*)&VtS[(n * 16 + l15) * 32 + quad * 8];
      O[0][n] = mfma_bf16(aP[0], bv, O[0][n]);
      O[1][n] = mfma_bf16(aP[1], bv, O[1][n]);
    }
  }

  // ---- epilogue: raw O (bf16), m, l partials ----
  unsigned short* Ob = Opart + ((size_t)(part * 32 + bh)) * T_ * DH;
  float* mrow = mP + (size_t)(part * 32 + bh) * T_;
  float* lrow = lP + (size_t)(part * 32 + bh) * T_;
  #pragma unroll
  for (int rt = 0; rt < 2; ++rt) {
    #pragma unroll
    for (int r = 0; r < 4; ++r) {
      const int t = qt0 + w * 32 + rt * 16 + quad * 4 + r;
      if (l15 == 0) { mrow[t] = m_i[rt][r]; lrow[t] = l_i[rt][r]; }
      #pragma unroll
      for (int n = 0; n < 8; ++n)
        Ob[(size_t)t * DH + n * 16 + l15] = f2bf(O[rt][n][r]);
    }
  }
}

// ---------------------------------------------------------------------------
// Split-K combine: xo = x + merge(O0,O1). 8 rows/block, grid = 65536/8.
// ---------------------------------------------------------------------------
__global__ __launch_bounds__(256) void comb_kernel(
    const unsigned short* __restrict__ Opart,
    const float* __restrict__ mP, const float* __restrict__ lP,
    const float* __restrict__ x, float* __restrict__ xo) {
  const int rid = blockIdx.x * 8 + (threadIdx.x >> 5);    // bh*2048 + t
  const int d4  = (threadIdx.x & 31) << 2;
  const int bh = rid >> 11, t = rid & (T_ - 1);
  const float m0 = mP[rid], m1 = mP[rid + 32 * T_];
  const float l0 = lP[rid], l1 = lP[rid + 32 * T_];
  const float m  = fmaxf(m0, m1);
  const float a0 = exp2f(m0 - m), a1 = exp2f(m1 - m);
  const float inv = 1.0f / (l0 * a0 + l1 * a1);
  const size_t o0 = (size_t)rid * DH + d4;
  const ushort4 u0 = *(const ushort4*)(Opart + o0);
  const ushort4 u1 = *(const ushort4*)(Opart + o0 + (size_t)32 * T_ * DH);
  const int b = bh >> 3, hh = bh & 7;
  const size_t xi = ((size_t)(b * T_ + t)) * C_ + hh * DH + d4;
  const float4 xv = *(const float4*)(x + xi);
  float4 ov;
  ov.x = xv.x + (bf2f(u0.x) * a0 + bf2f(u1.x) * a1) * inv;
  ov.y = xv.y + (bf2f(u0.y) * a0 + bf2f(u1.y) * a1) * inv;
  ov.z = xv.z + (bf2f(u0.z) * a0 + bf2f(u1.z) * a1) * inv;
  ov.w = xv.w + (bf2f(u0.w) * a0 + bf2f(u1.w) * a1) * inv;
  *(float4*)(xo + xi) = ov;
}

// ---------------------------------------------------------------------------
// Workspace layout (MB offsets):
//   0-32    xo    f32 [M][C]
//   32-48   q_hi  bf16 [bh][t][d] (pre-scaled)   \
//   48-64   q_lo  bf16 [bh][t][d]                 \
//   64-80   k_hi  bf16 image [bh][64][4][32][32]   } ff1 aliases 32-96 after attn
//   80-96   k_lo  bf16 image                      /
//   96-112  vimg  bf16 image [bh][64][128][32]
//   112-144 h_hi/h_lo bf16 [M][C]  -- ALSO Opart bf16 [2][32][T][DH] during attn
//   144-152 w1t   bf16 [DFF][C]
//   152-160 w2t   bf16 [C][DFF]
//   160-166 wt_hi bf16 [3H][DH][C]
//   166-172 wt_lo bf16 [3H][DH][C]
//   172-173 mP f32 [2][32][T]
//   173-174 lP f32 [2][32][T]
// ---------------------------------------------------------------------------
extern "C" void kernel_launch(void* const* d_in, const int* in_sizes, int n_in,
                              void* d_out, int out_size, void* d_ws, size_t ws_size,
                              hipStream_t stream) {
  (void)in_sizes; (void)n_in; (void)out_size; (void)ws_size;
  const float* x     = (const float*)d_in[0];
  const float* wq    = (const float*)d_in[1];
  const float* wk    = (const float*)d_in[2];
  const float* wv    = (const float*)d_in[3];
  const float* w1    = (const float*)d_in[4];
  const float* b1    = (const float*)d_in[5];
  const float* w2    = (const float*)d_in[6];
  const float* b2    = (const float*)d_in[7];
  const float* ln1_g = (const float*)d_in[8];
  const float* ln1_b = (const float*)d_in[9];
  const float* ln2_g = (const float*)d_in[10];
  const float* ln2_b = (const float*)d_in[11];
  float* out = (float*)d_out;

  char* W = (char*)d_ws;
  float* xo = (float*)(W);
  unsigned short* q_hi  = (unsigned short*)(W + (32u  << 20));
  unsigned short* q_lo  = (unsigned short*)(W + (48u  << 20));
  unsigned short* k_hi  = (unsigned short*)(W + (64u  << 20));
  unsigned short* k_lo  = (unsigned short*)(W + (80u  << 20));
  unsigned short* vimg  = (unsigned short*)(W + (96u  << 20));
  unsigned short* ff1   = (unsigned short*)(W + (32u  << 20));   // aliases q/k
  unsigned short* h_hi  = (unsigned short*)(W + (112u << 20));
  unsigned short* h_lo  = (unsigned short*)(W + (128u << 20));
  unsigned short* Opart = (unsigned short*)(W + (112u << 20));   // aliases h during attn
  unsigned short* w1t   = (unsigned short*)(W + (144u << 20));
  unsigned short* w2t   = (unsigned short*)(W + (152u << 20));
  unsigned short* wt_hi = (unsigned short*)(W + (160u << 20));
  unsigned short* wt_lo = (unsigned short*)(W + (166u << 20));
  float*          mPf   = (float*)(W + (172u << 20));
  float*          lPf   = (float*)(W + (173u << 20));

  cvt_t_kernel<<<dim3(DFF / 32, C_ / 32), 256, 0, stream>>>(w1, w1t, C_, DFF);
  cvt_t_kernel<<<dim3(C_ / 32, DFF / 32), 256, 0, stream>>>(w2, w2t, DFF, C_);
  cvt_qkv_kernel<<<dim3(DH / 32, C_ / 32, 24), 256, 0, stream>>>(wq, wk, wv, wt_hi, wt_lo);
  ln_kernel<<<M_, 256, 0, stream>>>(x, ln1_g, ln1_b, h_hi, h_lo);
  qkm_kernel<<<dim3(M_ / 128, 16), 256, 0, stream>>>(h_hi, h_lo, wt_hi, wt_lo,
                                                     q_hi, q_lo, k_hi, k_lo);
  vm_kernel<<<dim3(M_ / 128, H_), 256, 0, stream>>>(h_hi, wt_hi, vimg);
  attn_kernel<<<dim3(T_ / BQ, B_ * H_, 2), 256, 0, stream>>>(q_hi, q_lo, k_hi, k_lo,
                                                             vimg, Opart, mPf, lPf);
  comb_kernel<<<(32 * T_) / 8, 256, 0, stream>>>(Opart, mPf, lPf, x, xo);
  ln_kernel<<<M_, 256, 0, stream>>>(xo, ln2_g, ln2_b, h_hi, h_lo);
  ff1_kernel<<<dim3(DFF / 128, M_ / 128), 256, 0, stream>>>(h_hi, w1t, b1, ff1);
  ff2_kernel<<<dim3(C_ / 128, M_ / 128), 256, 0, stream>>>(ff1, w2t, b2, xo, out);
}